// Round 1
// baseline (721.965 us; speedup 1.0000x reference)
//
#include <hip/hip_runtime.h>
#include <math.h>

#define BATCH 8
#define CDIM 256
#define NDIM 2048
#define SCALE 0.0625f  // 1/sqrt(256)

// ---------------------------------------------------------------------------
// GEMM1 (TN): W[b,i,j] = SCALE * sum_c K[b,c,i] * Q[b,c,j]
// Both operands have the reduction dim (c) as the slow axis -> direct,
// fully-coalesced float4 staging into LDS. 128x128 tile, KT=16, 256 thr,
// 8x8 micro-tile per thread (split 4+4 for float4 LDS reads / global stores).
// ---------------------------------------------------------------------------
__global__ __launch_bounds__(256) void gemm1_kernel(const float* __restrict__ Q,
                                                    const float* __restrict__ K,
                                                    float* __restrict__ W) {
    __shared__ float As[16][128];  // K tile: As[c][i]
    __shared__ float Bs[16][128];  // Q tile: Bs[c][j]
    const int b  = blockIdx.z;
    const int i0 = blockIdx.y * 128;
    const int j0 = blockIdx.x * 128;
    const float* Kb = K + (size_t)b * CDIM * NDIM;
    const float* Qb = Q + (size_t)b * CDIM * NDIM;
    float* Wb = W + (size_t)b * NDIM * NDIM;

    const int tid = threadIdx.x;
    const int tx = tid & 15;        // col group
    const int ty = tid >> 4;        // row group
    const int lc = tid >> 5;        // 0..7  (k-row for loads)
    const int lx = (tid & 31) * 4;  // 0..124 (col for loads)

    float acc[8][8];
#pragma unroll
    for (int u = 0; u < 8; ++u)
#pragma unroll
        for (int w = 0; w < 8; ++w) acc[u][w] = 0.f;

    for (int k0 = 0; k0 < CDIM; k0 += 16) {
        *(float4*)&As[lc][lx]     = *(const float4*)&Kb[(size_t)(k0 + lc) * NDIM + i0 + lx];
        *(float4*)&As[lc + 8][lx] = *(const float4*)&Kb[(size_t)(k0 + lc + 8) * NDIM + i0 + lx];
        *(float4*)&Bs[lc][lx]     = *(const float4*)&Qb[(size_t)(k0 + lc) * NDIM + j0 + lx];
        *(float4*)&Bs[lc + 8][lx] = *(const float4*)&Qb[(size_t)(k0 + lc + 8) * NDIM + j0 + lx];
        __syncthreads();
#pragma unroll
        for (int kk = 0; kk < 16; ++kk) {
            float4 a0 = *(const float4*)&As[kk][ty * 4];
            float4 a1 = *(const float4*)&As[kk][64 + ty * 4];
            float4 b0 = *(const float4*)&Bs[kk][tx * 4];
            float4 b1 = *(const float4*)&Bs[kk][64 + tx * 4];
            float a[8]  = {a0.x, a0.y, a0.z, a0.w, a1.x, a1.y, a1.z, a1.w};
            float bb[8] = {b0.x, b0.y, b0.z, b0.w, b1.x, b1.y, b1.z, b1.w};
#pragma unroll
            for (int u = 0; u < 8; ++u)
#pragma unroll
                for (int w = 0; w < 8; ++w) acc[u][w] += a[u] * bb[w];
        }
        __syncthreads();
    }

#pragma unroll
    for (int u = 0; u < 8; ++u) {
        int i = i0 + ((u < 4) ? (ty * 4 + u) : (64 + ty * 4 + (u - 4)));
        float4 s0 = make_float4(acc[u][0] * SCALE, acc[u][1] * SCALE,
                                acc[u][2] * SCALE, acc[u][3] * SCALE);
        float4 s1 = make_float4(acc[u][4] * SCALE, acc[u][5] * SCALE,
                                acc[u][6] * SCALE, acc[u][7] * SCALE);
        *(float4*)&Wb[(size_t)i * NDIM + j0 + tx * 4]      = s0;
        *(float4*)&Wb[(size_t)i * NDIM + j0 + 64 + tx * 4] = s1;
    }
}

// ---------------------------------------------------------------------------
// Column softmax in place: W[b,i,j] <- exp(W-max_i)/sum_i exp(W-max_i)
// Block: 256 threads = 64 columns x 4 row-quarters (512 rows each).
// Row reads are coalesced (64 contiguous floats per quarter). Cross-quarter
// reduction via LDS (quarters live in different waves).
// ---------------------------------------------------------------------------
__global__ __launch_bounds__(256) void softmax_kernel(float* __restrict__ W) {
    const int b = blockIdx.y;
    const int base = threadIdx.x & 63;
    const int j = blockIdx.x * 64 + base;
    const int q = threadIdx.x >> 6;  // 0..3
    float* Wb = W + (size_t)b * NDIM * NDIM;
    __shared__ float red[256];

    float m = -1e30f;
    for (int ii = 0; ii < 512; ++ii)
        m = fmaxf(m, Wb[(size_t)(q * 512 + ii) * NDIM + j]);
    red[threadIdx.x] = m;
    __syncthreads();
    m = fmaxf(fmaxf(red[base], red[base + 64]), fmaxf(red[base + 128], red[base + 192]));
    __syncthreads();

    float s = 0.f;
    for (int ii = 0; ii < 512; ++ii)
        s += __expf(Wb[(size_t)(q * 512 + ii) * NDIM + j] - m);
    red[threadIdx.x] = s;
    __syncthreads();
    s = (red[base] + red[base + 64]) + (red[base + 128] + red[base + 192]);
    const float inv = 1.f / s;

    for (int ii = 0; ii < 512; ++ii) {
        size_t idx = (size_t)(q * 512 + ii) * NDIM + j;
        Wb[idx] = __expf(Wb[idx] - m) * inv;
    }
}

// ---------------------------------------------------------------------------
// GEMM2 (NN): out[b,c,j] = sum_i V[b,c,i] * W[b,i,j]
// M=256(c), N=2048(j), K=2048(i). 64x128 tile, KT=16, 256 thr, 4x8 micro.
// A (V) needs a transpose into LDS (As[k][c], padded to 68 to keep 16B
// alignment and break bank strides).
// ---------------------------------------------------------------------------
__global__ __launch_bounds__(256) void gemm2_kernel(const float* __restrict__ V,
                                                    const float* __restrict__ W,
                                                    float* __restrict__ Out) {
    __shared__ float As[16][68];   // V^T tile: As[k][c]
    __shared__ float Bs[16][128];  // W tile:  Bs[k][j]
    const int b  = blockIdx.z;
    const int c0 = blockIdx.y * 64;
    const int j0 = blockIdx.x * 128;
    const float* Vb = V + (size_t)b * CDIM * NDIM;
    const float* Wb = W + (size_t)b * NDIM * NDIM;
    float* Ob = Out + (size_t)b * CDIM * NDIM;

    const int tid = threadIdx.x;
    const int tx = tid & 15;        // cols tx*4+{0..3} and +64
    const int ty = tid >> 4;        // rows ty*4+{0..3}
    const int akq = tid & 3;        // k-quad for A load
    const int ac  = tid >> 2;       // 0..63 (c for A load)
    const int lc = tid >> 5;        // 0..7
    const int lx = (tid & 31) * 4;

    float acc[4][8];
#pragma unroll
    for (int u = 0; u < 4; ++u)
#pragma unroll
        for (int w = 0; w < 8; ++w) acc[u][w] = 0.f;

    for (int k0 = 0; k0 < NDIM; k0 += 16) {
        float4 av = *(const float4*)&Vb[(size_t)(c0 + ac) * NDIM + k0 + akq * 4];
        As[akq * 4 + 0][ac] = av.x;
        As[akq * 4 + 1][ac] = av.y;
        As[akq * 4 + 2][ac] = av.z;
        As[akq * 4 + 3][ac] = av.w;
        *(float4*)&Bs[lc][lx]     = *(const float4*)&Wb[(size_t)(k0 + lc) * NDIM + j0 + lx];
        *(float4*)&Bs[lc + 8][lx] = *(const float4*)&Wb[(size_t)(k0 + lc + 8) * NDIM + j0 + lx];
        __syncthreads();
#pragma unroll
        for (int kk = 0; kk < 16; ++kk) {
            float4 a0 = *(const float4*)&As[kk][ty * 4];
            float4 b0 = *(const float4*)&Bs[kk][tx * 4];
            float4 b1 = *(const float4*)&Bs[kk][64 + tx * 4];
            float a[4]  = {a0.x, a0.y, a0.z, a0.w};
            float bb[8] = {b0.x, b0.y, b0.z, b0.w, b1.x, b1.y, b1.z, b1.w};
#pragma unroll
            for (int u = 0; u < 4; ++u)
#pragma unroll
                for (int w = 0; w < 8; ++w) acc[u][w] += a[u] * bb[w];
        }
        __syncthreads();
    }

#pragma unroll
    for (int u = 0; u < 4; ++u) {
        int c = c0 + ty * 4 + u;
        float4 s0 = make_float4(acc[u][0], acc[u][1], acc[u][2], acc[u][3]);
        float4 s1 = make_float4(acc[u][4], acc[u][5], acc[u][6], acc[u][7]);
        *(float4*)&Ob[(size_t)c * NDIM + j0 + tx * 4]      = s0;
        *(float4*)&Ob[(size_t)c * NDIM + j0 + 64 + tx * 4] = s1;
    }
}

extern "C" void kernel_launch(void* const* d_in, const int* in_sizes, int n_in,
                              void* d_out, int out_size, void* d_ws, size_t ws_size,
                              hipStream_t stream) {
    const float* q = (const float*)d_in[0];
    const float* k = (const float*)d_in[1];
    const float* v = (const float*)d_in[2];
    float* out = (float*)d_out;
    float* w   = out + (size_t)BATCH * CDIM * NDIM;  // weights region of d_out

    dim3 g1(NDIM / 128, NDIM / 128, BATCH);
    gemm1_kernel<<<g1, 256, 0, stream>>>(q, k, w);

    dim3 gs(NDIM / 64, BATCH);
    softmax_kernel<<<gs, 256, 0, stream>>>(w);

    dim3 g2(NDIM / 128, CDIM / 64, BATCH);
    gemm2_kernel<<<g2, 256, 0, stream>>>(v, w, out);
}

// Round 2
// 330.503 us; speedup vs baseline: 2.1844x; 2.1844x over previous
//
#include <hip/hip_runtime.h>
#include <math.h>

#define BATCH 8
#define CDIM 256
#define NDIM 2048
#define SCALE 0.0625f  // 1/sqrt(256)

typedef _Float16 half8v __attribute__((ext_vector_type(8)));
typedef _Float16 half4v __attribute__((ext_vector_type(4)));
typedef float floatx4 __attribute__((ext_vector_type(4)));

// workspace offsets (bytes)
#define WS_S    0
#define WS_INVS 65536
#define WS_KT   131072
#define WS_QT   (131072 + 8388608)
#define WS_VH   (131072 + 2 * 8388608)
// total ws use: ~25.3 MB

// ---------------------------------------------------------------------------
// prep: K,Q -> fp16 transposed+tiled [b][ib(16)][cb(8)][i(128)][c(32)]
//       V   -> fp16 tiled            [b][cb(4)][ib(32)][c(64)][i(64)]
// These layouts make GEMM staging a contiguous half8 copy (no transpose).
// ---------------------------------------------------------------------------
__global__ __launch_bounds__(256) void prep_kernel(const float* __restrict__ Q,
                                                   const float* __restrict__ K,
                                                   const float* __restrict__ V,
                                                   _Float16* __restrict__ Kt,
                                                   _Float16* __restrict__ Qt,
                                                   _Float16* __restrict__ Vh) {
    const int g = blockIdx.x * 256 + threadIdx.x;
    const int mat = blockIdx.y;
    if (mat < 2) {
        const float* src = (mat == 0) ? K : Q;
        _Float16* dst = (mat == 0) ? Kt : Qt;
        const int b = g >> 15, r = g & 32767;
        const int iq = r & 511, cq = r >> 9;  // i-quad (512), c-quad (64)
        const float* p = src + (size_t)b * CDIM * NDIM + (size_t)(cq * 4) * NDIM + iq * 4;
        float fr[4][4];
        *(float4*)fr[0] = *(const float4*)(p);
        *(float4*)fr[1] = *(const float4*)(p + NDIM);
        *(float4*)fr[2] = *(const float4*)(p + 2 * NDIM);
        *(float4*)fr[3] = *(const float4*)(p + 3 * NDIM);
        const int cb = cq >> 3, cc0 = (cq & 7) * 4;
#pragma unroll
        for (int ii = 0; ii < 4; ++ii) {
            const int i = iq * 4 + ii;
            const int ib = i >> 7, il = i & 127;
            half4v h = {(_Float16)fr[0][ii], (_Float16)fr[1][ii],
                        (_Float16)fr[2][ii], (_Float16)fr[3][ii]};
            *(half4v*)&dst[((((size_t)(b * 16 + ib) * 8 + cb) * 128 + il) * 32) + cc0] = h;
        }
    } else {
        const int R = g >> 2, part = g & 3;
        const int cl = R & 63, ibv = (R >> 6) & 31, cbv = (R >> 11) & 3, b = R >> 13;
        const int c = cbv * 64 + cl, i0 = ibv * 64 + part * 16;
        const float* p = V + (size_t)(b * CDIM + c) * NDIM + i0;
        _Float16* d = Vh + ((((size_t)(b * 4 + cbv) * 32 + ibv) * 64 + cl) * 64 + part * 16);
#pragma unroll
        for (int u = 0; u < 4; ++u) {
            float4 f = *(const float4*)(p + u * 4);
            half4v h = {(_Float16)f.x, (_Float16)f.y, (_Float16)f.z, (_Float16)f.w};
            *(half4v*)(d + u * 4) = h;
        }
    }
}

// ---------------------------------------------------------------------------
// GEMM1: E[b,i,j] = exp(SCALE * sum_c K[c,i]*Q[c,j]); f16 MFMA 16x16x32.
// Block 128x128, waves 2x2 (wave tile 64x64 = 4x4 mfma tiles), BK=32, 8 iters.
// LDS rows stride 40 halves (80B): 16B-aligned b128 frag reads, 2-way banks.
// ---------------------------------------------------------------------------
__global__ __launch_bounds__(256) void gemm1_kernel(const _Float16* __restrict__ Kt,
                                                    const _Float16* __restrict__ Qt,
                                                    float* __restrict__ E) {
    __shared__ _Float16 Al[128 * 40];
    __shared__ _Float16 Bl[128 * 40];
    const int b = blockIdx.z, ib = blockIdx.y, jb = blockIdx.x;
    const _Float16* Ab = Kt + (size_t)(b * 16 + ib) * 8 * 4096;
    const _Float16* Bb = Qt + (size_t)(b * 16 + jb) * 8 * 4096;
    const int t = threadIdx.x, wave = t >> 6, lane = t & 63;
    const int wy = wave >> 1, wx = wave & 1, quad = lane >> 4, lr = lane & 15;
    floatx4 acc[4][4] = {};
    const int ci0 = t * 2, ci1 = t * 2 + 1;
    _Float16* wA0 = &Al[(ci0 >> 2) * 40 + (ci0 & 3) * 8];
    _Float16* wA1 = &Al[(ci1 >> 2) * 40 + (ci1 & 3) * 8];
    _Float16* wB0 = &Bl[(ci0 >> 2) * 40 + (ci0 & 3) * 8];
    _Float16* wB1 = &Bl[(ci1 >> 2) * 40 + (ci1 & 3) * 8];

    for (int cb = 0; cb < 8; ++cb) {
        half8v a0 = *(const half8v*)(Ab + cb * 4096 + ci0 * 8);
        half8v a1 = *(const half8v*)(Ab + cb * 4096 + ci1 * 8);
        half8v b0 = *(const half8v*)(Bb + cb * 4096 + ci0 * 8);
        half8v b1 = *(const half8v*)(Bb + cb * 4096 + ci1 * 8);
        __syncthreads();
        *(half8v*)wA0 = a0; *(half8v*)wA1 = a1;
        *(half8v*)wB0 = b0; *(half8v*)wB1 = b1;
        __syncthreads();
        half8v af[4], bf[4];
#pragma unroll
        for (int m = 0; m < 4; ++m)
            af[m] = *(const half8v*)&Al[(wy * 64 + m * 16 + lr) * 40 + quad * 8];
#pragma unroll
        for (int n = 0; n < 4; ++n)
            bf[n] = *(const half8v*)&Bl[(wx * 64 + n * 16 + lr) * 40 + quad * 8];
#pragma unroll
        for (int m = 0; m < 4; ++m)
#pragma unroll
            for (int n = 0; n < 4; ++n)
                acc[m][n] = __builtin_amdgcn_mfma_f32_16x16x32_f16(af[m], bf[n], acc[m][n], 0, 0, 0);
    }

    float* Eb = E + (size_t)b * NDIM * NDIM;
    const int col0 = jb * 128 + wx * 64;
#pragma unroll
    for (int m = 0; m < 4; ++m) {
        const int row0 = ib * 128 + wy * 64 + m * 16 + quad * 4;
#pragma unroll
        for (int n = 0; n < 4; ++n) {
            const int col = col0 + n * 16 + lr;
#pragma unroll
            for (int r = 0; r < 4; ++r)
                Eb[(size_t)(row0 + r) * NDIM + col] = __expf(acc[m][n][r] * SCALE);
        }
    }
}

// ---------------------------------------------------------------------------
// colsum: S[b,j] += sum over a 256-row chunk of E[b,:,j] (atomics, 8 chunks)
// ---------------------------------------------------------------------------
__global__ __launch_bounds__(256) void colsum_kernel(const float* __restrict__ E,
                                                     float* __restrict__ S) {
    const int b = blockIdx.z, ic = blockIdx.y;
    const int j = blockIdx.x * 256 + threadIdx.x;
    const float* Eb = E + (size_t)b * NDIM * NDIM + (size_t)ic * 256 * NDIM + j;
    float s = 0.f;
#pragma unroll 8
    for (int ii = 0; ii < 256; ++ii) s += Eb[(size_t)ii * NDIM];
    atomicAdd(&S[b * NDIM + j], s);
}

__global__ __launch_bounds__(256) void inv_kernel(const float* __restrict__ S,
                                                  float* __restrict__ invS) {
    const int x = blockIdx.x * 256 + threadIdx.x;
    invS[x] = 1.0f / S[x];
}

// normalize: W <- E * invS[col]  (weights output, fp32, in place)
__global__ __launch_bounds__(256) void normalize_kernel(float* __restrict__ W,
                                                        const float* __restrict__ invS) {
    const size_t flat = ((size_t)blockIdx.x * 256 + threadIdx.x) * 4;
    const int b = (int)(flat >> 22);
    const int j = (int)(flat & 2047);
    float4 e = *(float4*)&W[flat];
    float4 iv = *(const float4*)&invS[b * NDIM + j];
    float4 w = make_float4(e.x * iv.x, e.y * iv.y, e.z * iv.z, e.w * iv.w);
    *(float4*)&W[flat] = w;
}

// ---------------------------------------------------------------------------
// GEMM2: out[b,c,j] = sum_i V[c,i] * W[i,j]; f16 MFMA. Block 64x128,
// waves 2x2 (wave 32x64 = 2x4 tiles), BK=64 (32 iters). A from tiled Vh
// (contiguous copy); B = W fp32 micro-transposed in-kernel into XOR-swizzled
// LDS (stride 72, swizzle ((j>>2)&7)*8 -> ~4-way writes, ~free reads).
// ---------------------------------------------------------------------------
__global__ __launch_bounds__(256) void gemm2_kernel(const _Float16* __restrict__ Vh,
                                                    const float* __restrict__ W,
                                                    float* __restrict__ Out) {
    __shared__ _Float16 Al2[64 * 72];
    __shared__ _Float16 Bl2[128 * 72];
    const int b = blockIdx.z, cb = blockIdx.y, jb = blockIdx.x;
    const int t = threadIdx.x, wave = t >> 6, lane = t & 63;
    const int wy = wave >> 1, wx = wave & 1, quad = lane >> 4, lr = lane & 15;
    const _Float16* Abase = Vh + (size_t)(b * 4 + cb) * 32 * 4096;
    const float* Wb = W + (size_t)b * NDIM * NDIM;
    const int j0 = jb * 128;
    floatx4 acc[2][4] = {};
    const int ci0 = t * 2, ci1 = t * 2 + 1;
    const int jq = t & 31, ih0 = t >> 5;

    for (int it = 0; it < 32; ++it) {
        half8v a0 = *(const half8v*)(Abase + it * 4096 + ci0 * 8);
        half8v a1 = *(const half8v*)(Abase + it * 4096 + ci1 * 8);
        float fb[2][4][4];
#pragma unroll
        for (int h = 0; h < 2; ++h) {
            const int iq = ih0 + h * 8;
#pragma unroll
            for (int ii = 0; ii < 4; ++ii)
                *(float4*)fb[h][ii] =
                    *(const float4*)&Wb[(size_t)(it * 64 + iq * 4 + ii) * NDIM + j0 + jq * 4];
        }
        __syncthreads();
        *(half8v*)&Al2[(ci0 >> 3) * 72 + (ci0 & 7) * 8] = a0;
        *(half8v*)&Al2[(ci1 >> 3) * 72 + (ci1 & 7) * 8] = a1;
#pragma unroll
        for (int h = 0; h < 2; ++h) {
            const int iq = ih0 + h * 8;
#pragma unroll
            for (int jj = 0; jj < 4; ++jj) {
                const int j = jq * 4 + jj;
                half4v hv = {(_Float16)fb[h][0][jj], (_Float16)fb[h][1][jj],
                             (_Float16)fb[h][2][jj], (_Float16)fb[h][3][jj]};
                *(half4v*)&Bl2[j * 72 + ((iq * 4) ^ ((jq & 7) * 8))] = hv;
            }
        }
        __syncthreads();
#pragma unroll
        for (int ks = 0; ks < 2; ++ks) {
            half8v af[2], bf[4];
#pragma unroll
            for (int m = 0; m < 2; ++m)
                af[m] = *(const half8v*)&Al2[(wy * 32 + m * 16 + lr) * 72 + ks * 32 + quad * 8];
#pragma unroll
            for (int n = 0; n < 4; ++n) {
                const int j = wx * 64 + n * 16 + lr;
                bf[n] = *(const half8v*)&Bl2[j * 72 + ((ks * 32 + quad * 8) ^ (((j >> 2) & 7) * 8))];
            }
#pragma unroll
            for (int m = 0; m < 2; ++m)
#pragma unroll
                for (int n = 0; n < 4; ++n)
                    acc[m][n] = __builtin_amdgcn_mfma_f32_16x16x32_f16(af[m], bf[n], acc[m][n], 0, 0, 0);
        }
    }

    float* Ob = Out + (size_t)b * CDIM * NDIM;
#pragma unroll
    for (int m = 0; m < 2; ++m) {
        const int c0r = cb * 64 + wy * 32 + m * 16 + quad * 4;
#pragma unroll
        for (int n = 0; n < 4; ++n) {
            const int j = j0 + wx * 64 + n * 16 + lr;
#pragma unroll
            for (int r = 0; r < 4; ++r)
                Ob[(size_t)(c0r + r) * NDIM + j] = acc[m][n][r];
        }
    }
}

extern "C" void kernel_launch(void* const* d_in, const int* in_sizes, int n_in,
                              void* d_out, int out_size, void* d_ws, size_t ws_size,
                              hipStream_t stream) {
    const float* q = (const float*)d_in[0];
    const float* k = (const float*)d_in[1];
    const float* v = (const float*)d_in[2];
    float* out = (float*)d_out;
    float* w = out + (size_t)BATCH * CDIM * NDIM;  // weights region

    char* ws = (char*)d_ws;
    float* S = (float*)(ws + WS_S);
    float* invS = (float*)(ws + WS_INVS);
    _Float16* Kt = (_Float16*)(ws + WS_KT);
    _Float16* Qt = (_Float16*)(ws + WS_QT);
    _Float16* Vh = (_Float16*)(ws + WS_VH);

    hipMemsetAsync(S, 0, BATCH * NDIM * sizeof(float), stream);
    prep_kernel<<<dim3(1024, 3), 256, 0, stream>>>(q, k, v, Kt, Qt, Vh);
    gemm1_kernel<<<dim3(16, 16, 8), 256, 0, stream>>>(Kt, Qt, w);
    colsum_kernel<<<dim3(8, 8, 8), 256, 0, stream>>>(w, S);
    inv_kernel<<<64, 256, 0, stream>>>(S, invS);
    normalize_kernel<<<32768, 256, 0, stream>>>(w, invS);
    gemm2_kernel<<<dim3(16, 4, 8), 256, 0, stream>>>(Vh, w, out);
}

// Round 3
// 318.430 us; speedup vs baseline: 2.2673x; 1.0379x over previous
//
#include <hip/hip_runtime.h>
#include <math.h>

#define BATCH 8
#define CDIM 256
#define NDIM 2048
#define SCALE 0.0625f  // 1/sqrt(256)

typedef _Float16 half8v __attribute__((ext_vector_type(8)));
typedef _Float16 half4v __attribute__((ext_vector_type(4)));
typedef float floatx4 __attribute__((ext_vector_type(4)));

// workspace offsets (bytes)
#define WS_INVS 0
#define WS_KT   65536
#define WS_QT   (65536 + 8388608)
#define WS_EHT  (65536 + 2 * 8388608)
// total ws use: ~84 MB

// ---------------------------------------------------------------------------
// prep: K,Q -> fp16 transposed+tiled [b][ib(16)][cb(8)][i(128)][c(32)]
// ---------------------------------------------------------------------------
__global__ __launch_bounds__(256) void prep_kernel(const float* __restrict__ Q,
                                                   const float* __restrict__ K,
                                                   _Float16* __restrict__ Kt,
                                                   _Float16* __restrict__ Qt) {
    const int g = blockIdx.x * 256 + threadIdx.x;
    const float* src = (blockIdx.y == 0) ? K : Q;
    _Float16* dst = (blockIdx.y == 0) ? Kt : Qt;
    const int b = g >> 15, r = g & 32767;
    const int iq = r & 511, cq = r >> 9;  // i-quad (512), c-quad (64)
    const float* p = src + (size_t)b * CDIM * NDIM + (size_t)(cq * 4) * NDIM + iq * 4;
    float fr[4][4];
    *(float4*)fr[0] = *(const float4*)(p);
    *(float4*)fr[1] = *(const float4*)(p + NDIM);
    *(float4*)fr[2] = *(const float4*)(p + 2 * NDIM);
    *(float4*)fr[3] = *(const float4*)(p + 3 * NDIM);
    const int cb = cq >> 3, cc0 = (cq & 7) * 4;
#pragma unroll
    for (int ii = 0; ii < 4; ++ii) {
        const int i = iq * 4 + ii;
        const int ib = i >> 7, il = i & 127;
        half4v h = {(_Float16)fr[0][ii], (_Float16)fr[1][ii],
                    (_Float16)fr[2][ii], (_Float16)fr[3][ii]};
        *(half4v*)&dst[((((size_t)(b * 16 + ib) * 8 + cb) * 128 + il) * 32) + cc0] = h;
    }
}

// ---------------------------------------------------------------------------
// GEMM1: E = exp(SCALE * K^T Q). Main loop identical to r2 (proven). Epilogue:
// exp -> fp16 -> LDS 128x128 chunk-swizzled transpose -> coalesced half8
// stores to EhT[b][jb(32)][ib(32)][jl(64)][il(64)] (gemm2 B layout, j-major).
// ---------------------------------------------------------------------------
__global__ __launch_bounds__(256) void gemm1_kernel(const _Float16* __restrict__ Kt,
                                                    const _Float16* __restrict__ Qt,
                                                    _Float16* __restrict__ EhT) {
    __shared__ _Float16 Al[128 * 40];
    __shared__ _Float16 Bl[128 * 40];
    __shared__ _Float16 LT[128 * 128];
    const int b = blockIdx.z, ib2 = blockIdx.y, jb2 = blockIdx.x;
    const _Float16* Ab = Kt + (size_t)(b * 16 + ib2) * 8 * 4096;
    const _Float16* Bb = Qt + (size_t)(b * 16 + jb2) * 8 * 4096;
    const int t = threadIdx.x, wave = t >> 6, lane = t & 63;
    const int wy = wave >> 1, wx = wave & 1, quad = lane >> 4, lr = lane & 15;
    floatx4 acc[4][4] = {};
    const int ci0 = t * 2, ci1 = t * 2 + 1;
    _Float16* wA0 = &Al[(ci0 >> 2) * 40 + (ci0 & 3) * 8];
    _Float16* wA1 = &Al[(ci1 >> 2) * 40 + (ci1 & 3) * 8];
    _Float16* wB0 = &Bl[(ci0 >> 2) * 40 + (ci0 & 3) * 8];
    _Float16* wB1 = &Bl[(ci1 >> 2) * 40 + (ci1 & 3) * 8];

    for (int cb = 0; cb < 8; ++cb) {
        half8v a0 = *(const half8v*)(Ab + cb * 4096 + ci0 * 8);
        half8v a1 = *(const half8v*)(Ab + cb * 4096 + ci1 * 8);
        half8v b0 = *(const half8v*)(Bb + cb * 4096 + ci0 * 8);
        half8v b1 = *(const half8v*)(Bb + cb * 4096 + ci1 * 8);
        __syncthreads();
        *(half8v*)wA0 = a0; *(half8v*)wA1 = a1;
        *(half8v*)wB0 = b0; *(half8v*)wB1 = b1;
        __syncthreads();
        half8v af[4], bf[4];
#pragma unroll
        for (int m = 0; m < 4; ++m)
            af[m] = *(const half8v*)&Al[(wy * 64 + m * 16 + lr) * 40 + quad * 8];
#pragma unroll
        for (int n = 0; n < 4; ++n)
            bf[n] = *(const half8v*)&Bl[(wx * 64 + n * 16 + lr) * 40 + quad * 8];
#pragma unroll
        for (int m = 0; m < 4; ++m)
#pragma unroll
            for (int n = 0; n < 4; ++n)
                acc[m][n] = __builtin_amdgcn_mfma_f32_16x16x32_f16(af[m], bf[n], acc[m][n], 0, 0, 0);
    }

    // epilogue: exp -> LDS transpose (chunk-swizzled) -> EhT
#pragma unroll
    for (int m = 0; m < 4; ++m) {
#pragma unroll
        for (int n = 0; n < 4; ++n) {
            const int j_loc = wx * 64 + n * 16 + lr;
#pragma unroll
            for (int r = 0; r < 4; ++r) {
                const int i_loc = wy * 64 + m * 16 + quad * 4 + r;
                float e = __expf(acc[m][n][r] * SCALE);
                LT[j_loc * 128 + (((i_loc >> 3) ^ (j_loc & 7)) << 3) + (i_loc & 7)] = (_Float16)e;
            }
        }
    }
    __syncthreads();
    const int jh = wave >> 1, ih = wave & 1;
    _Float16* dst = EhT + ((size_t)((b * 32 + jb2 * 2 + jh) * 32) + ib2 * 2 + ih) * 4096;
#pragma unroll
    for (int cc = 0; cc < 8; ++cc) {
        const int j = jh * 64 + cc * 8 + (lane >> 3);
        half8v h = *(const half8v*)&LT[j * 128 + (((ih * 8 + (lane & 7)) ^ (lane >> 3)) << 3)];
        *(half8v*)&dst[cc * 512 + lane * 8] = h;
    }
}

// ---------------------------------------------------------------------------
// colsum: invS[b,j] = 1 / sum_i E[i,j]. EhT is j-major so this is a coalesced
// row sum. One wave per j row; shuffle reduce; no atomics, no memset.
// ---------------------------------------------------------------------------
__global__ __launch_bounds__(256) void colsum_kernel(const _Float16* __restrict__ EhT,
                                                     float* __restrict__ invS) {
    const int w = threadIdx.x >> 6, l = threadIdx.x & 63;
    const int R = blockIdx.x * 4 + w;  // 0..16383
    const int b = R >> 11, j = R & 2047;
    const int jb = j >> 6, jl = j & 63;
    const _Float16* base = EhT + ((size_t)(b * 32 + jb) * 32) * 4096 + jl * 64;
    float s = 0.f;
#pragma unroll
    for (int u = 0; u < 4; ++u) {
        const int flat = u * 64 + l;  // 0..255 half8 chunks of the row
        const int ib = flat >> 3, c8 = flat & 7;
        half8v h = *(const half8v*)(base + (size_t)ib * 4096 + c8 * 8);
#pragma unroll
        for (int e = 0; e < 8; ++e) s += (float)h[e];
    }
#pragma unroll
    for (int off = 32; off; off >>= 1) s += __shfl_xor(s, off, 64);
    if (l == 0) invS[b * 2048 + j] = 1.0f / s;
}

// ---------------------------------------------------------------------------
// normalize-transpose: W[b,i,j] = EhT[b][jb][ib][j][i] * invS[b,j], fp32.
// 64x64 tiles via chunk-swizzled LDS; coalesced half8 in, float4 out.
// ---------------------------------------------------------------------------
__global__ __launch_bounds__(256) void normt_kernel(const _Float16* __restrict__ EhT,
                                                    const float* __restrict__ invS,
                                                    float* __restrict__ W) {
    __shared__ _Float16 LT[64 * 64];
    const int ib = blockIdx.x, jb = blockIdx.y, b = blockIdx.z;
    const int t = threadIdx.x;
    const _Float16* tile = EhT + ((size_t)((b * 32 + jb) * 32 + ib)) * 4096;
#pragma unroll
    for (int u = 0; u < 2; ++u) {
        const int f = u * 256 + t;  // half8 index 0..511
        const int jl = f >> 3, c = f & 7;
        half8v h = *(const half8v*)(tile + f * 8);
        *(half8v*)&LT[jl * 64 + ((c ^ (jl & 7)) << 3)] = h;
    }
    __syncthreads();
    const int jq = t & 15, ir = t >> 4;
    float iv[4];
#pragma unroll
    for (int jj = 0; jj < 4; ++jj) iv[jj] = invS[b * 2048 + jb * 64 + jq * 4 + jj];
    float* Wb = W + ((size_t)(b * 2048 + ib * 64)) * 2048 + jb * 64;
#pragma unroll
    for (int p = 0; p < 4; ++p) {
        const int i = p * 16 + ir;
        float vals[4];
#pragma unroll
        for (int jj = 0; jj < 4; ++jj) {
            const int j = jq * 4 + jj;
            _Float16 h = LT[j * 64 + (((i >> 3) ^ (j & 7)) << 3) + (i & 7)];
            vals[jj] = (float)h * iv[jj];
        }
        *(float4*)&Wb[(size_t)i * 2048 + jq * 4] =
            make_float4(vals[0], vals[1], vals[2], vals[3]);
    }
}

// ---------------------------------------------------------------------------
// GEMM2: out[b,c,j] = invS[j] * sum_i V[c,i] * E[i,j]. Block 128c x 128j,
// full K (2048) per block, grid 16x2x8 = 256. A staged from fp32 V directly
// (V is [c][i], i-contiguous -> no transpose); B from EhT (contiguous copy).
// LDS row stride 72 halves (144B, 16B-aligned, 2-way-free banks).
// ---------------------------------------------------------------------------
__global__ __launch_bounds__(256) void gemm2_kernel(const float* __restrict__ V,
                                                    const _Float16* __restrict__ EhT,
                                                    const float* __restrict__ invS,
                                                    float* __restrict__ Out) {
    __shared__ _Float16 As[128 * 72];
    __shared__ _Float16 Bs[128 * 72];
    const int b = blockIdx.z, cc2 = blockIdx.y, jb2 = blockIdx.x;
    const int t = threadIdx.x, wave = t >> 6, lane = t & 63;
    const int wy = wave >> 1, wx = wave & 1, quad = lane >> 4, lr = lane & 15;
    const float* Vb = V + ((size_t)(b * 256 + cc2 * 128)) * 2048;
    floatx4 acc[4][4] = {};

    for (int it = 0; it < 32; ++it) {
        float4 av[8];
#pragma unroll
        for (int u = 0; u < 8; ++u) {
            const int f = u * 256 + t;
            const int c = f >> 4, i4 = f & 15;
            av[u] = *(const float4*)&Vb[(size_t)c * 2048 + it * 64 + i4 * 4];
        }
        half8v bv[4];
#pragma unroll
        for (int u = 0; u < 4; ++u) {
            const int f = u * 256 + t;  // 0..1023
            const int jl = f >> 3, c8 = f & 7;
            const int jb = jb2 * 2 + (jl >> 6);
            bv[u] = *(const half8v*)&EhT[((size_t)((b * 32 + jb) * 32) + it) * 4096 +
                                         (jl & 63) * 64 + c8 * 8];
        }
        __syncthreads();
#pragma unroll
        for (int u = 0; u < 8; ++u) {
            const int f = u * 256 + t;
            const int c = f >> 4, i4 = f & 15;
            half4v h = {(_Float16)av[u].x, (_Float16)av[u].y,
                        (_Float16)av[u].z, (_Float16)av[u].w};
            *(half4v*)&As[c * 72 + i4 * 4] = h;
        }
#pragma unroll
        for (int u = 0; u < 4; ++u) {
            const int f = u * 256 + t;
            const int jl = f >> 3, c8 = f & 7;
            *(half8v*)&Bs[jl * 72 + c8 * 8] = bv[u];
        }
        __syncthreads();
#pragma unroll
        for (int ks = 0; ks < 2; ++ks) {
            half8v af[4], bf[4];
#pragma unroll
            for (int m = 0; m < 4; ++m)
                af[m] = *(const half8v*)&As[(wy * 64 + m * 16 + lr) * 72 + ks * 32 + quad * 8];
#pragma unroll
            for (int n = 0; n < 4; ++n)
                bf[n] = *(const half8v*)&Bs[(wx * 64 + n * 16 + lr) * 72 + ks * 32 + quad * 8];
#pragma unroll
            for (int m = 0; m < 4; ++m)
#pragma unroll
                for (int n = 0; n < 4; ++n)
                    acc[m][n] = __builtin_amdgcn_mfma_f32_16x16x32_f16(af[m], bf[n], acc[m][n], 0, 0, 0);
        }
    }

    float* Ob = Out + ((size_t)(b * 256 + cc2 * 128)) * 2048 + jb2 * 128;
    float iv[4];
#pragma unroll
    for (int n = 0; n < 4; ++n)
        iv[n] = invS[b * 2048 + jb2 * 128 + wx * 64 + n * 16 + lr];
#pragma unroll
    for (int m = 0; m < 4; ++m) {
        const int c0r = wy * 64 + m * 16 + quad * 4;
#pragma unroll
        for (int n = 0; n < 4; ++n) {
            const int j = wx * 64 + n * 16 + lr;
#pragma unroll
            for (int r = 0; r < 4; ++r)
                Ob[(size_t)(c0r + r) * 2048 + j] = acc[m][n][r] * iv[n];
        }
    }
}

extern "C" void kernel_launch(void* const* d_in, const int* in_sizes, int n_in,
                              void* d_out, int out_size, void* d_ws, size_t ws_size,
                              hipStream_t stream) {
    const float* q = (const float*)d_in[0];
    const float* k = (const float*)d_in[1];
    const float* v = (const float*)d_in[2];
    float* out = (float*)d_out;
    float* w = out + (size_t)BATCH * CDIM * NDIM;  // weights region

    char* ws = (char*)d_ws;
    float* invS = (float*)(ws + WS_INVS);
    _Float16* Kt = (_Float16*)(ws + WS_KT);
    _Float16* Qt = (_Float16*)(ws + WS_QT);
    _Float16* EhT = (_Float16*)(ws + WS_EHT);

    prep_kernel<<<dim3(1024, 2), 256, 0, stream>>>(q, k, Kt, Qt);
    gemm1_kernel<<<dim3(16, 16, 8), 256, 0, stream>>>(Kt, Qt, EhT);
    colsum_kernel<<<4096, 256, 0, stream>>>(EhT, invS);
    normt_kernel<<<dim3(32, 32, 8), 256, 0, stream>>>(EhT, invS, w);
    gemm2_kernel<<<dim3(16, 2, 8), 256, 0, stream>>>(v, EhT, invS, out);
}